// Round 4
// baseline (257.900 us; speedup 1.0000x reference)
//
#include <hip/hip_runtime.h>
#include <stdint.h>

#define D 128
#define E_EDGES 50000
#define S_NEG 16
#define N_A 100000
#define N_B 50000
#define ES (E_EDGES * S_NEG)

#define GA1 500       // scan1 A blocks: 200 rows each = 100000 exactly
#define GB1 250       // scan1 B blocks: 200 rows each = 50000 exactly
#define NCPY 16       // replicated svec copies for atomic reduction

#define S2_ROWS 128   // scan2 rows per block
#define GA2 ((N_A + S2_ROWS - 1) / S2_ROWS)   // 782
#define GB2 ((N_B + S2_ROWS - 1) / S2_ROWS)   // 391

// hist flat-segment geometry (int4 units)
#define NT_U 200000               // nt0 / nt1 each: 800000 ints
#define EIT_U 12500               // ei tails: 50000 ints
#define FLAT_U (2 * NT_U + 2 * EIT_U)   // 425000
// zero region: cntA (4*N_A) + cntB (2*N_B) + svec (NCPY*6*D) floats
#define ZERO_F4 ((4 * N_A + 2 * N_B + NCPY * 6 * D) / 4)   // 128072

__device__ inline float dot4(float4 a, float4 b) {
    return a.x * b.x + a.y * b.y + a.z * b.z + a.w * b.w;
}
__device__ inline void fma16(float* acc, const float4 w, const float4 x) {
    acc[0]  += w.x * x.x; acc[1]  += w.x * x.y; acc[2]  += w.x * x.z; acc[3]  += w.x * x.w;
    acc[4]  += w.y * x.x; acc[5]  += w.y * x.y; acc[6]  += w.y * x.z; acc[7]  += w.y * x.w;
    acc[8]  += w.z * x.x; acc[9]  += w.z * x.y; acc[10] += w.z * x.z; acc[11] += w.z * x.w;
    acc[12] += w.w * x.x; acc[13] += w.w * x.y; acc[14] += w.w * x.z; acc[15] += w.w * x.w;
}
__device__ inline void fma8(float* acc, const float2 w, const float4 x) {
    acc[0] += w.x * x.x; acc[1] += w.x * x.y; acc[2] += w.x * x.z; acc[3] += w.x * x.w;
    acc[4] += w.y * x.x; acc[5] += w.y * x.y; acc[6] += w.y * x.z; acc[7] += w.y * x.w;
}

// ---------------------------------------------------------------------------
// ws layout (floats):
//   cntA[4*N_A]   interleaved per-row counts {pos0, nh0, nh1, nt0}
//   cntB[2*N_B]   interleaved {pos1, nt1}
//   svec[NCPY][6*D] replicated weighted sums (A0..A3,B0,B1)
//   cvec[6*D]
//   PA[5*N_A] (SoA planes), PB[N_B]
// ---------------------------------------------------------------------------

__global__ void k_zero(float4* __restrict__ dst) {
    const int nth = gridDim.x * blockDim.x;
    for (int u = blockIdx.x * blockDim.x + threadIdx.x; u < ZERO_F4; u += nth)
        dst[u] = make_float4(0.f, 0.f, 0.f, 0.f);
}

// Direct global-atomic float histogram: no slabs, no LDS, no privatization.
// 1.8M scattered device-scope atomicAdds over 550K bins — far-atomic path.
__global__ void k_hist(const int* __restrict__ ei0, const int* __restrict__ ei1,
                       const int* __restrict__ nh0, const int* __restrict__ nh1,
                       const int* __restrict__ nt0, const int* __restrict__ nt1,
                       float* __restrict__ cntA, float* __restrict__ cntB) {
    const int t0 = blockIdx.x * blockDim.x + threadIdx.x;
    const int nth = gridDim.x * blockDim.x;

    // flat int4 segments: nt0 -> cntA[4i+3], nt1 -> cntB[2i+1],
    //                     ei0 tails -> cntA[4i+0], ei1 tails -> cntB[2i+0]
    for (int u = t0; u < FLAT_U; u += nth) {
        int4 v; float* b; int s, o;
        if (u < NT_U) {
            v = reinterpret_cast<const int4*>(nt0)[u];            b = cntA; s = 4; o = 3;
        } else if (u < 2 * NT_U) {
            v = reinterpret_cast<const int4*>(nt1)[u - NT_U];     b = cntB; s = 2; o = 1;
        } else if (u < 2 * NT_U + EIT_U) {
            v = reinterpret_cast<const int4*>(ei0 + E_EDGES)[u - 2 * NT_U];
            b = cntA; s = 4; o = 0;
        } else {
            v = reinterpret_cast<const int4*>(ei1 + E_EDGES)[u - 2 * NT_U - EIT_U];
            b = cntB; s = 2; o = 0;
        }
        atomicAdd(b + (size_t)v.x * s + o, 1.f);
        atomicAdd(b + (size_t)v.y * s + o, 1.f);
        atomicAdd(b + (size_t)v.z * s + o, 1.f);
        atomicAdd(b + (size_t)v.w * s + o, 1.f);
    }
    // strided segments: nh0/nh1 column 0 (stride S_NEG)
    for (int u = t0; u < 2 * E_EDGES; u += nth) {
        if (u < E_EDGES)
            atomicAdd(&cntA[4 * (size_t)nh0[(size_t)u * S_NEG] + 1], 1.f);
        else
            atomicAdd(&cntA[4 * (size_t)nh1[(size_t)(u - E_EDGES) * S_NEG] + 2], 1.f);
    }
}

// Weighted table scan: per-row counts now ONE coalesced float4/float2 load,
// 5x5 double-buffered streaming pipeline, 16-copy atomic svec reduce.
__global__ void __launch_bounds__(256, 4)
k_scan1(const float* __restrict__ embA, const float* __restrict__ embB,
        const float* __restrict__ cntA, const float* __restrict__ cntB,
        float* __restrict__ svec) {
    __shared__ float sds[4 * 512];
    __shared__ float4 cwbuf[200];
    const int tid = threadIdx.x;
    const int l = tid & 31;
    const int grp = tid >> 5;      // 0..7, 25 rows each
    const int wid = tid >> 6;      // 0..3
    float* svdst = svec + (size_t)(blockIdx.x & (NCPY - 1)) * (6 * D);

    if ((int)blockIdx.x < GA1) {
        const int nb = blockIdx.x * 200;
        if (tid < 200)
            cwbuf[tid] = reinterpret_cast<const float4*>(cntA)[nb + tid];
        __syncthreads();

        const int r0 = nb + grp * 25;
        const int lr0 = grp * 25;
        const float* base = embA + 4 * l;
        float acc[16];
#pragma unroll
        for (int k = 0; k < 16; ++k) acc[k] = 0.f;
        float4 wc[5], xc[5];
#pragma unroll
        for (int u = 0; u < 5; ++u) {
            wc[u] = cwbuf[lr0 + u];
            xc[u] = *reinterpret_cast<const float4*>(base + (size_t)(r0 + u) * D);
        }
#pragma unroll
        for (int b = 0; b < 5; ++b) {
            float4 wn[5], xn[5];
            if (b < 4) {
#pragma unroll
                for (int u = 0; u < 5; ++u) {
                    const int rr = (b + 1) * 5 + u;
                    wn[u] = cwbuf[lr0 + rr];
                    xn[u] = *reinterpret_cast<const float4*>(base + (size_t)(r0 + rr) * D);
                }
            }
#pragma unroll
            for (int u = 0; u < 5; ++u) fma16(acc, wc[u], xc[u]);
            if (b < 4) {
#pragma unroll
                for (int u = 0; u < 5; ++u) { wc[u] = wn[u]; xc[u] = xn[u]; }
            }
        }
#pragma unroll
        for (int k = 0; k < 16; ++k) acc[k] += __shfl_xor(acc[k], 32);
        if ((tid & 32) == 0) {
            float* w0 = sds + wid * 512;
#pragma unroll
            for (int p = 0; p < 4; ++p)
                *reinterpret_cast<float4*>(w0 + p * 128 + 4 * l) =
                    make_float4(acc[4 * p], acc[4 * p + 1], acc[4 * p + 2], acc[4 * p + 3]);
        }
        __syncthreads();
        for (int j = tid; j < 512; j += 256)
            atomicAdd(&svdst[j], sds[j] + sds[512 + j] + sds[1024 + j] + sds[1536 + j]);
    } else {
        const int nb = (blockIdx.x - GA1) * 200;
        if (tid < 200)
            reinterpret_cast<float2*>(cwbuf)[tid] =
                reinterpret_cast<const float2*>(cntB)[nb + tid];
        __syncthreads();
        const float2* cw2 = reinterpret_cast<const float2*>(cwbuf);

        const int r0 = nb + grp * 25;
        const int lr0 = grp * 25;
        const float* base = embB + 4 * l;
        float acc[8];
#pragma unroll
        for (int k = 0; k < 8; ++k) acc[k] = 0.f;
        float2 wc[5]; float4 xc[5];
#pragma unroll
        for (int u = 0; u < 5; ++u) {
            wc[u] = cw2[lr0 + u];
            xc[u] = *reinterpret_cast<const float4*>(base + (size_t)(r0 + u) * D);
        }
#pragma unroll
        for (int b = 0; b < 5; ++b) {
            float2 wn[5]; float4 xn[5];
            if (b < 4) {
#pragma unroll
                for (int u = 0; u < 5; ++u) {
                    const int rr = (b + 1) * 5 + u;
                    wn[u] = cw2[lr0 + rr];
                    xn[u] = *reinterpret_cast<const float4*>(base + (size_t)(r0 + rr) * D);
                }
            }
#pragma unroll
            for (int u = 0; u < 5; ++u) fma8(acc, wc[u], xc[u]);
            if (b < 4) {
#pragma unroll
                for (int u = 0; u < 5; ++u) { wc[u] = wn[u]; xc[u] = xn[u]; }
            }
        }
#pragma unroll
        for (int k = 0; k < 8; ++k) acc[k] += __shfl_xor(acc[k], 32);
        if ((tid & 32) == 0) {
            float* w0 = sds + wid * 256;
#pragma unroll
            for (int p = 0; p < 2; ++p)
                *reinterpret_cast<float4*>(w0 + p * 128 + 4 * l) =
                    make_float4(acc[4 * p], acc[4 * p + 1], acc[4 * p + 2], acc[4 * p + 3]);
        }
        __syncthreads();
        for (int j = tid; j < 256; j += 256)
            atomicAdd(&svdst[512 + j], sds[j] + sds[256 + j] + sds[512 + j] + sds[768 + j]);
    }
}

// One-block micro-kernel: reduce the NCPY svec copies, then
// cvec_j = scale_j * K_{j&1} @ s_plane(j). Kernel boundary = the fence.
__global__ void k_cvec(const float* __restrict__ rel, const float* __restrict__ svec,
                       float* __restrict__ cvec) {
    __shared__ float sv[6 * D];
    const int tid = threadIdx.x;    // 256
    for (int e = tid; e < 6 * D; e += 256) {
        float s = 0.f;
#pragma unroll
        for (int c = 0; c < NCPY; ++c) s += svec[c * (6 * D) + e];
        sv[e] = s;
    }
    __syncthreads();
    // output order: pos0,pos1,nh0,nh1,nt0,nt1 ; sv planes: A0,A1,A2,A3,B0,B1
    for (int e = tid; e < 6 * D; e += 256) {
        const int j = e >> 7, i = e & 127;
        const int plane = (j == 0) ? 0 : (j == 1) ? 4 : (j == 5) ? 5 : (j - 1);
        const float4* Kp4 = reinterpret_cast<const float4*>(
            rel + (size_t)(j & 1) * (D * D) + (size_t)i * D);
        const float* s = sv + plane * D;
        float acc = 0.f;
#pragma unroll
        for (int k = 0; k < 32; ++k) {
            const float4 kk = Kp4[k];
            acc += kk.x * s[4 * k] + kk.y * s[4 * k + 1]
                 + kk.z * s[4 * k + 2] + kk.w * s[4 * k + 3];
        }
        cvec[j * D + i] = acc * ((j == 2 || j == 3) ? (float)S_NEG : 1.0f);
    }
}

// 16 lanes per row: fully-consumed contiguous loads (4 rows / wave instr),
// register-resident c slices, 4-level shfl_xor reduce per plane.
__global__ void k_scan2(const float* __restrict__ embA, const float* __restrict__ embB,
                        const float* __restrict__ cvec,
                        float* __restrict__ PA, float* __restrict__ PB) {
    const int tid = threadIdx.x;
    const int sub = tid & 15;          // element-slot within row (8 floats each)
    const int rloc = tid >> 4;         // 0..15: row-slot within block-iteration

    if ((int)blockIdx.x < GA2) {
        float4 c0[5], c1[5];
#pragma unroll
        for (int j = 0; j < 5; ++j) {
            c0[j] = *reinterpret_cast<const float4*>(cvec + j * D + sub * 8);
            c1[j] = *reinterpret_cast<const float4*>(cvec + j * D + sub * 8 + 4);
        }
        const int base = blockIdx.x * S2_ROWS;
#pragma unroll 2
        for (int it = 0; it < S2_ROWS / 16; ++it) {
            const int row = base + it * 16 + rloc;
            const int rc = min(row, N_A - 1);
            const float* rp = embA + (size_t)rc * D + sub * 8;
            const float4 x0 = *reinterpret_cast<const float4*>(rp);
            const float4 x1 = *reinterpret_cast<const float4*>(rp + 4);
            float p0 = dot4(x0, c0[0]) + dot4(x1, c1[0]);
            float p1 = dot4(x0, c0[1]) + dot4(x1, c1[1]);
            float p2 = dot4(x0, c0[2]) + dot4(x1, c1[2]);
            float p3 = dot4(x0, c0[3]) + dot4(x1, c1[3]);
            float p4 = dot4(x0, c0[4]) + dot4(x1, c1[4]);
#pragma unroll
            for (int m = 1; m < 16; m <<= 1) {
                p0 += __shfl_xor(p0, m);
                p1 += __shfl_xor(p1, m);
                p2 += __shfl_xor(p2, m);
                p3 += __shfl_xor(p3, m);
                p4 += __shfl_xor(p4, m);
            }
            if (row < N_A) {
                if (sub == 0)      PA[row] = p0;
                else if (sub == 1) PA[(size_t)N_A + row] = p1;
                else if (sub == 2) PA[(size_t)2 * N_A + row] = p2;
                else if (sub == 3) PA[(size_t)3 * N_A + row] = p3;
                else if (sub == 4) PA[(size_t)4 * N_A + row] = p4;
            }
        }
    } else {
        const float4 c0 = *reinterpret_cast<const float4*>(cvec + 5 * D + sub * 8);
        const float4 c1 = *reinterpret_cast<const float4*>(cvec + 5 * D + sub * 8 + 4);
        const int base = (blockIdx.x - GA2) * S2_ROWS;
#pragma unroll 2
        for (int it = 0; it < S2_ROWS / 16; ++it) {
            const int row = base + it * 16 + rloc;
            const int rc = min(row, N_B - 1);
            const float* rp = embB + (size_t)rc * D + sub * 8;
            const float4 x0 = *reinterpret_cast<const float4*>(rp);
            const float4 x1 = *reinterpret_cast<const float4*>(rp + 4);
            float p = dot4(x0, c0) + dot4(x1, c1);
#pragma unroll
            for (int m = 1; m < 16; m <<= 1) p += __shfl_xor(p, m);
            if (row < N_B && sub == 0) PB[row] = p;
        }
    }
}

// Vectorized scatter from SoA planes: int4 index loads, float4 stores.
__global__ void k_scatter(const int* __restrict__ ei0, const int* __restrict__ ei1,
                          const int* __restrict__ nh0, const int* __restrict__ nh1,
                          const int* __restrict__ nt0, const int* __restrict__ nt1,
                          const float* __restrict__ PA, const float* __restrict__ PB,
                          float* __restrict__ out) {
    const int total4 = (2 * E_EDGES + 4 * ES) / 4;  // 825000
    const float* P0 = PA;
    const float* P1 = PA + (size_t)N_A;
    const float* P2 = PA + (size_t)2 * N_A;
    const float* P3 = PA + (size_t)3 * N_A;
    const float* P4 = PA + (size_t)4 * N_A;
    for (int t = blockIdx.x * blockDim.x + threadIdx.x; t < total4;
         t += gridDim.x * blockDim.x) {
        const int e = t * 4;
        float4 v;
        if (e < E_EDGES) {
            const int4 i4 = *reinterpret_cast<const int4*>(ei0 + e);
            v = make_float4(P0[i4.x], P0[i4.y], P0[i4.z], P0[i4.w]);
        } else if (e < 2 * E_EDGES) {
            const int4 i4 = *reinterpret_cast<const int4*>(ei1 + (e - E_EDGES));
            v = make_float4(P1[i4.x], P1[i4.y], P1[i4.z], P1[i4.w]);
        } else if (e < 2 * E_EDGES + ES) {
            const int4 i4 = *reinterpret_cast<const int4*>(nh0 + (e - 2 * E_EDGES));
            v = make_float4(P2[i4.x], P2[i4.y], P2[i4.z], P2[i4.w]);
        } else if (e < 2 * E_EDGES + 2 * ES) {
            const int4 i4 = *reinterpret_cast<const int4*>(nh1 + (e - 2 * E_EDGES - ES));
            v = make_float4(P3[i4.x], P3[i4.y], P3[i4.z], P3[i4.w]);
        } else if (e < 2 * E_EDGES + 3 * ES) {
            const int i = e - 2 * E_EDGES - 2 * ES;
            const float s = P4[nt0[(i >> 4) << 4]];
            v = make_float4(s, s, s, s);
        } else {
            const int i = e - 2 * E_EDGES - 3 * ES;
            const float s = PB[nt1[(i >> 4) << 4]];
            v = make_float4(s, s, s, s);
        }
        *reinterpret_cast<float4*>(out + e) = v;
    }
}

extern "C" void kernel_launch(void* const* d_in, const int* in_sizes, int n_in,
                              void* d_out, int out_size, void* d_ws, size_t ws_size,
                              hipStream_t stream) {
    const float* embA = (const float*)d_in[0];
    const float* embB = (const float*)d_in[1];
    const float* rel  = (const float*)d_in[2];
    const int* ei0 = (const int*)d_in[3];
    const int* ei1 = (const int*)d_in[4];
    const int* nh0 = (const int*)d_in[5];
    const int* nh1 = (const int*)d_in[6];
    const int* nt0 = (const int*)d_in[7];
    const int* nt1 = (const int*)d_in[8];
    float* out = (float*)d_out;

    float* cntA = (float*)d_ws;                               // 4*N_A
    float* cntB = cntA + (size_t)4 * N_A;                     // 2*N_B
    float* svec = cntB + (size_t)2 * N_B;                     // NCPY*6*D
    float* cvec = svec + (size_t)NCPY * 6 * D;                // 6*D
    float* PA   = cvec + 6 * D;                               // 5*N_A (SoA)
    float* PB   = PA + (size_t)5 * N_A;                       // N_B

    k_zero<<<64, 256, 0, stream>>>((float4*)d_ws);
    k_hist<<<512, 256, 0, stream>>>(ei0, ei1, nh0, nh1, nt0, nt1, cntA, cntB);
    k_scan1<<<GA1 + GB1, 256, 0, stream>>>(embA, embB, cntA, cntB, svec);
    k_cvec<<<1, 256, 0, stream>>>(rel, svec, cvec);
    k_scan2<<<GA2 + GB2, 256, 0, stream>>>(embA, embB, cvec, PA, PB);
    k_scatter<<<2048, 256, 0, stream>>>(ei0, ei1, nh0, nh1, nt0, nt1, PA, PB, out);
}

// Round 5
// 191.996 us; speedup vs baseline: 1.3433x; 1.3433x over previous
//
#include <hip/hip_runtime.h>
#include <stdint.h>

#define D 128
#define E_EDGES 50000
#define S_NEG 16
#define N_A 100000
#define N_B 50000
#define ES (E_EDGES * S_NEG)

#define HW 12500      // LDS hist words (50000 bins as packed bytes)
#define ACH 38        // A-source chunks of 25000 items (2+2+2+32)
#define BCH 34        // B-source chunks of 25000 items (2+32)

#define GA1 500       // scan1 A blocks: 200 rows each = 100000 exactly
#define GB1 250       // scan1 B blocks: 200 rows each = 50000 exactly
#define NCPY 16       // replicated svec copies for atomic reduction

#define S2_ROWS 128   // scan2 rows per block
#define GA2 ((N_A + S2_ROWS - 1) / S2_ROWS)   // 782
#define GB2 ((N_B + S2_ROWS - 1) / S2_ROWS)   // 391

__device__ inline float dot4(float4 a, float4 b) {
    return a.x * b.x + a.y * b.y + a.z * b.z + a.w * b.w;
}
__device__ inline void fma16(float* acc, const float4 w, const float4 x) {
    acc[0]  += w.x * x.x; acc[1]  += w.x * x.y; acc[2]  += w.x * x.z; acc[3]  += w.x * x.w;
    acc[4]  += w.y * x.x; acc[5]  += w.y * x.y; acc[6]  += w.y * x.z; acc[7]  += w.y * x.w;
    acc[8]  += w.z * x.x; acc[9]  += w.z * x.y; acc[10] += w.z * x.z; acc[11] += w.z * x.w;
    acc[12] += w.w * x.x; acc[13] += w.w * x.y; acc[14] += w.w * x.z; acc[15] += w.w * x.w;
}
__device__ inline void fma8(float* acc, const float2 w, const float4 x) {
    acc[0] += w.x * x.x; acc[1] += w.x * x.y; acc[2] += w.x * x.z; acc[3] += w.x * x.w;
    acc[4] += w.y * x.x; acc[5] += w.y * x.y; acc[6] += w.y * x.z; acc[7] += w.y * x.w;
}

// ---------------------------------------------------------------------------
// ws layout (4-byte words):
//   u32   partA[76*HW], partB[34*HW]   byte-hist slabs (slab = chunk*2+half / chunk)
//   f32   cntA[4*N_A]  interleaved per-row counts {pos0, nh0, nh1, nt0}
//   f32   cntB[2*N_B]  interleaved {pos1, nt1}
//   f32   svec[NCPY][6*D]  replicated weighted sums (A0..A3,B0,B1)
//   f32   cvec[6*D]
//   f32   PA[5*N_A] (SoA planes), PB[N_B]
// Lessons encoded here: LDS-privatized hist + slab fold (round 4: far-atomics
// = HBM RMW, 56 MB writes); no in-kernel __threadfence (round 2: ~120 ns/block
// L2-flush bill); kernel boundary is the cheap cross-XCD fence.
// ---------------------------------------------------------------------------

__global__ void k_hist(const int* __restrict__ ei0, const int* __restrict__ ei1,
                       const int* __restrict__ nh0, const int* __restrict__ nh1,
                       const int* __restrict__ nt0, const int* __restrict__ nt1,
                       uint32_t* __restrict__ partA, uint32_t* __restrict__ partB,
                       float* __restrict__ svec) {
    __shared__ uint32_t h[HW];
    const int tid = threadIdx.x;   // 512
    if (blockIdx.x == 0) {         // zero atomic target (ws is poisoned)
        for (int i = tid; i < NCPY * 6 * D; i += 512) svec[i] = 0.f;
    }
    for (int w = tid; w < HW; w += 512) h[w] = 0;
    __syncthreads();

    const int b = blockIdx.x;
    if (b < 2 * ACH) {             // A-table sources (two halves per chunk)
        const int c = b >> 1, hh = b & 1;
        const unsigned lo = hh * 50000u;
        uint32_t* dst = partA + (size_t)b * HW;
        if (c >= 2 && c < 6) {     // nh columns (stride 16): c 2-3 = nh0, 4-5 = nh1
            const int* src = (c < 4) ? nh0 : nh1;
            const long long base = (long long)(c & 1) * 25000 * S_NEG;
            for (int i = tid; i < 25000; i += 512) {
                const unsigned r = (unsigned)src[base + (long long)i * S_NEG] - lo;
                if (r < 50000u) atomicAdd(&h[r >> 2], 1u << ((r & 3u) * 8u));
            }
        } else {                   // flat int4: c 0-1 = ei0 tails, 6-37 = nt0
            const int* srcp = (c < 2) ? (ei0 + E_EDGES + c * 25000)
                                      : (nt0 + (c - 6) * 25000);
            const int4* src4 = reinterpret_cast<const int4*>(srcp);
            for (int i = tid; i < 6250; i += 512) {
                const int4 v = src4[i];
                unsigned r;
                r = (unsigned)v.x - lo; if (r < 50000u) atomicAdd(&h[r >> 2], 1u << ((r & 3u) * 8u));
                r = (unsigned)v.y - lo; if (r < 50000u) atomicAdd(&h[r >> 2], 1u << ((r & 3u) * 8u));
                r = (unsigned)v.z - lo; if (r < 50000u) atomicAdd(&h[r >> 2], 1u << ((r & 3u) * 8u));
                r = (unsigned)v.w - lo; if (r < 50000u) atomicAdd(&h[r >> 2], 1u << ((r & 3u) * 8u));
            }
        }
        __syncthreads();
        for (int w = tid; w < HW; w += 512) dst[w] = h[w];
    } else {                       // B-table sources
        const int c = b - 2 * ACH;
        uint32_t* dst = partB + (size_t)c * HW;
        const int* srcp = (c < 2) ? (ei1 + E_EDGES + c * 25000)
                                  : (nt1 + (c - 2) * 25000);
        const int4* src4 = reinterpret_cast<const int4*>(srcp);
        for (int i = tid; i < 6250; i += 512) {
            const int4 v = src4[i];
            unsigned r;
            r = (unsigned)v.x; if (r < 50000u) atomicAdd(&h[r >> 2], 1u << ((r & 3u) * 8u));
            r = (unsigned)v.y; if (r < 50000u) atomicAdd(&h[r >> 2], 1u << ((r & 3u) * 8u));
            r = (unsigned)v.z; if (r < 50000u) atomicAdd(&h[r >> 2], 1u << ((r & 3u) * 8u));
            r = (unsigned)v.w; if (r < 50000u) atomicAdd(&h[r >> 2], 1u << ((r & 3u) * 8u));
        }
        __syncthreads();
        for (int w = tid; w < HW; w += 512) dst[w] = h[w];
    }
}

// Fold byte-hist slabs into interleaved float counts (one row per thread).
__global__ void k_reduceC(const uint32_t* __restrict__ partA,
                          const uint32_t* __restrict__ partB,
                          float4* __restrict__ cntA, float2* __restrict__ cntB) {
    const int t = blockIdx.x * 256 + threadIdx.x;
    if (t < N_A) {
        const int n = t;
        const int hh = (n >= 50000);
        const int w = (n - hh * 50000) >> 2;
        const int sh = (n & 3) * 8;
        const uint32_t* p = partA + (size_t)hh * HW + w;
        unsigned s0 = 0, s1 = 0, s2 = 0, s3 = 0;
#pragma unroll
        for (int c = 0; c < 2; ++c)  s0 += (p[(size_t)(c * 2) * HW] >> sh) & 255u;
#pragma unroll
        for (int c = 2; c < 4; ++c)  s1 += (p[(size_t)(c * 2) * HW] >> sh) & 255u;
#pragma unroll
        for (int c = 4; c < 6; ++c)  s2 += (p[(size_t)(c * 2) * HW] >> sh) & 255u;
#pragma unroll 8
        for (int c = 6; c < 38; ++c) s3 += (p[(size_t)(c * 2) * HW] >> sh) & 255u;
        cntA[n] = make_float4((float)s0, (float)s1, (float)s2, (float)s3);
    } else if (t < N_A + N_B) {
        const int n = t - N_A;
        const int w = n >> 2;
        const int sh = (n & 3) * 8;
        const uint32_t* p = partB + w;
        unsigned s0 = 0, s1 = 0;
#pragma unroll
        for (int c = 0; c < 2; ++c)  s0 += (p[(size_t)c * HW] >> sh) & 255u;
#pragma unroll 8
        for (int c = 2; c < 34; ++c) s1 += (p[(size_t)c * HW] >> sh) & 255u;
        cntB[n] = make_float2((float)s0, (float)s1);
    }
}

// Weighted table scan: per-row counts are ONE coalesced float4/float2 load,
// 5x5 double-buffered streaming pipeline, 16-copy atomic svec reduce.
__global__ void __launch_bounds__(256, 4)
k_scan1(const float* __restrict__ embA, const float* __restrict__ embB,
        const float* __restrict__ cntA, const float* __restrict__ cntB,
        float* __restrict__ svec) {
    __shared__ float sds[4 * 512];
    __shared__ float4 cwbuf[200];
    const int tid = threadIdx.x;
    const int l = tid & 31;
    const int grp = tid >> 5;      // 0..7, 25 rows each
    const int wid = tid >> 6;      // 0..3
    float* svdst = svec + (size_t)(blockIdx.x & (NCPY - 1)) * (6 * D);

    if ((int)blockIdx.x < GA1) {
        const int nb = blockIdx.x * 200;
        if (tid < 200)
            cwbuf[tid] = reinterpret_cast<const float4*>(cntA)[nb + tid];
        __syncthreads();

        const int r0 = nb + grp * 25;
        const int lr0 = grp * 25;
        const float* base = embA + 4 * l;
        float acc[16];
#pragma unroll
        for (int k = 0; k < 16; ++k) acc[k] = 0.f;
        float4 wc[5], xc[5];
#pragma unroll
        for (int u = 0; u < 5; ++u) {
            wc[u] = cwbuf[lr0 + u];
            xc[u] = *reinterpret_cast<const float4*>(base + (size_t)(r0 + u) * D);
        }
#pragma unroll
        for (int b = 0; b < 5; ++b) {
            float4 wn[5], xn[5];
            if (b < 4) {
#pragma unroll
                for (int u = 0; u < 5; ++u) {
                    const int rr = (b + 1) * 5 + u;
                    wn[u] = cwbuf[lr0 + rr];
                    xn[u] = *reinterpret_cast<const float4*>(base + (size_t)(r0 + rr) * D);
                }
            }
#pragma unroll
            for (int u = 0; u < 5; ++u) fma16(acc, wc[u], xc[u]);
            if (b < 4) {
#pragma unroll
                for (int u = 0; u < 5; ++u) { wc[u] = wn[u]; xc[u] = xn[u]; }
            }
        }
#pragma unroll
        for (int k = 0; k < 16; ++k) acc[k] += __shfl_xor(acc[k], 32);
        if ((tid & 32) == 0) {
            float* w0 = sds + wid * 512;
#pragma unroll
            for (int p = 0; p < 4; ++p)
                *reinterpret_cast<float4*>(w0 + p * 128 + 4 * l) =
                    make_float4(acc[4 * p], acc[4 * p + 1], acc[4 * p + 2], acc[4 * p + 3]);
        }
        __syncthreads();
        for (int j = tid; j < 512; j += 256)
            atomicAdd(&svdst[j], sds[j] + sds[512 + j] + sds[1024 + j] + sds[1536 + j]);
    } else {
        const int nb = (blockIdx.x - GA1) * 200;
        if (tid < 200)
            reinterpret_cast<float2*>(cwbuf)[tid] =
                reinterpret_cast<const float2*>(cntB)[nb + tid];
        __syncthreads();
        const float2* cw2 = reinterpret_cast<const float2*>(cwbuf);

        const int r0 = nb + grp * 25;
        const int lr0 = grp * 25;
        const float* base = embB + 4 * l;
        float acc[8];
#pragma unroll
        for (int k = 0; k < 8; ++k) acc[k] = 0.f;
        float2 wc[5]; float4 xc[5];
#pragma unroll
        for (int u = 0; u < 5; ++u) {
            wc[u] = cw2[lr0 + u];
            xc[u] = *reinterpret_cast<const float4*>(base + (size_t)(r0 + u) * D);
        }
#pragma unroll
        for (int b = 0; b < 5; ++b) {
            float2 wn[5]; float4 xn[5];
            if (b < 4) {
#pragma unroll
                for (int u = 0; u < 5; ++u) {
                    const int rr = (b + 1) * 5 + u;
                    wn[u] = cw2[lr0 + rr];
                    xn[u] = *reinterpret_cast<const float4*>(base + (size_t)(r0 + rr) * D);
                }
            }
#pragma unroll
            for (int u = 0; u < 5; ++u) fma8(acc, wc[u], xc[u]);
            if (b < 4) {
#pragma unroll
                for (int u = 0; u < 5; ++u) { wc[u] = wn[u]; xc[u] = xn[u]; }
            }
        }
#pragma unroll
        for (int k = 0; k < 8; ++k) acc[k] += __shfl_xor(acc[k], 32);
        if ((tid & 32) == 0) {
            float* w0 = sds + wid * 256;
#pragma unroll
            for (int p = 0; p < 2; ++p)
                *reinterpret_cast<float4*>(w0 + p * 128 + 4 * l) =
                    make_float4(acc[4 * p], acc[4 * p + 1], acc[4 * p + 2], acc[4 * p + 3]);
        }
        __syncthreads();
        for (int j = tid; j < 256; j += 256)
            atomicAdd(&svdst[512 + j], sds[j] + sds[256 + j] + sds[512 + j] + sds[768 + j]);
    }
}

// One-block micro-kernel: reduce the NCPY svec copies, then
// cvec_j = scale_j * K_{j&1} @ s_plane(j). Kernel boundary = the fence.
__global__ void k_cvec(const float* __restrict__ rel, const float* __restrict__ svec,
                       float* __restrict__ cvec) {
    __shared__ float sv[6 * D];
    const int tid = threadIdx.x;    // 256
    for (int e = tid; e < 6 * D; e += 256) {
        float s = 0.f;
#pragma unroll
        for (int c = 0; c < NCPY; ++c) s += svec[c * (6 * D) + e];
        sv[e] = s;
    }
    __syncthreads();
    // output order: pos0,pos1,nh0,nh1,nt0,nt1 ; sv planes: A0,A1,A2,A3,B0,B1
    for (int e = tid; e < 6 * D; e += 256) {
        const int j = e >> 7, i = e & 127;
        const int plane = (j == 0) ? 0 : (j == 1) ? 4 : (j == 5) ? 5 : (j - 1);
        const float4* Kp4 = reinterpret_cast<const float4*>(
            rel + (size_t)(j & 1) * (D * D) + (size_t)i * D);
        const float* s = sv + plane * D;
        float acc = 0.f;
#pragma unroll
        for (int k = 0; k < 32; ++k) {
            const float4 kk = Kp4[k];
            acc += kk.x * s[4 * k] + kk.y * s[4 * k + 1]
                 + kk.z * s[4 * k + 2] + kk.w * s[4 * k + 3];
        }
        cvec[j * D + i] = acc * ((j == 2 || j == 3) ? (float)S_NEG : 1.0f);
    }
}

// 16 lanes per row: fully-consumed contiguous loads (4 rows / wave instr),
// register-resident c slices, 4-level shfl_xor reduce per plane.
__global__ void k_scan2(const float* __restrict__ embA, const float* __restrict__ embB,
                        const float* __restrict__ cvec,
                        float* __restrict__ PA, float* __restrict__ PB) {
    const int tid = threadIdx.x;
    const int sub = tid & 15;          // element-slot within row (8 floats each)
    const int rloc = tid >> 4;         // 0..15: row-slot within block-iteration

    if ((int)blockIdx.x < GA2) {
        float4 c0[5], c1[5];
#pragma unroll
        for (int j = 0; j < 5; ++j) {
            c0[j] = *reinterpret_cast<const float4*>(cvec + j * D + sub * 8);
            c1[j] = *reinterpret_cast<const float4*>(cvec + j * D + sub * 8 + 4);
        }
        const int base = blockIdx.x * S2_ROWS;
#pragma unroll 2
        for (int it = 0; it < S2_ROWS / 16; ++it) {
            const int row = base + it * 16 + rloc;
            const int rc = min(row, N_A - 1);
            const float* rp = embA + (size_t)rc * D + sub * 8;
            const float4 x0 = *reinterpret_cast<const float4*>(rp);
            const float4 x1 = *reinterpret_cast<const float4*>(rp + 4);
            float p0 = dot4(x0, c0[0]) + dot4(x1, c1[0]);
            float p1 = dot4(x0, c0[1]) + dot4(x1, c1[1]);
            float p2 = dot4(x0, c0[2]) + dot4(x1, c1[2]);
            float p3 = dot4(x0, c0[3]) + dot4(x1, c1[3]);
            float p4 = dot4(x0, c0[4]) + dot4(x1, c1[4]);
#pragma unroll
            for (int m = 1; m < 16; m <<= 1) {
                p0 += __shfl_xor(p0, m);
                p1 += __shfl_xor(p1, m);
                p2 += __shfl_xor(p2, m);
                p3 += __shfl_xor(p3, m);
                p4 += __shfl_xor(p4, m);
            }
            if (row < N_A) {
                if (sub == 0)      PA[row] = p0;
                else if (sub == 1) PA[(size_t)N_A + row] = p1;
                else if (sub == 2) PA[(size_t)2 * N_A + row] = p2;
                else if (sub == 3) PA[(size_t)3 * N_A + row] = p3;
                else if (sub == 4) PA[(size_t)4 * N_A + row] = p4;
            }
        }
    } else {
        const float4 c0 = *reinterpret_cast<const float4*>(cvec + 5 * D + sub * 8);
        const float4 c1 = *reinterpret_cast<const float4*>(cvec + 5 * D + sub * 8 + 4);
        const int base = (blockIdx.x - GA2) * S2_ROWS;
#pragma unroll 2
        for (int it = 0; it < S2_ROWS / 16; ++it) {
            const int row = base + it * 16 + rloc;
            const int rc = min(row, N_B - 1);
            const float* rp = embB + (size_t)rc * D + sub * 8;
            const float4 x0 = *reinterpret_cast<const float4*>(rp);
            const float4 x1 = *reinterpret_cast<const float4*>(rp + 4);
            float p = dot4(x0, c0) + dot4(x1, c1);
#pragma unroll
            for (int m = 1; m < 16; m <<= 1) p += __shfl_xor(p, m);
            if (row < N_B && sub == 0) PB[row] = p;
        }
    }
}

// Vectorized scatter from SoA planes: int4 index loads, float4 stores.
__global__ void k_scatter(const int* __restrict__ ei0, const int* __restrict__ ei1,
                          const int* __restrict__ nh0, const int* __restrict__ nh1,
                          const int* __restrict__ nt0, const int* __restrict__ nt1,
                          const float* __restrict__ PA, const float* __restrict__ PB,
                          float* __restrict__ out) {
    const int total4 = (2 * E_EDGES + 4 * ES) / 4;  // 825000
    const float* P0 = PA;
    const float* P1 = PA + (size_t)N_A;
    const float* P2 = PA + (size_t)2 * N_A;
    const float* P3 = PA + (size_t)3 * N_A;
    const float* P4 = PA + (size_t)4 * N_A;
    for (int t = blockIdx.x * blockDim.x + threadIdx.x; t < total4;
         t += gridDim.x * blockDim.x) {
        const int e = t * 4;
        float4 v;
        if (e < E_EDGES) {
            const int4 i4 = *reinterpret_cast<const int4*>(ei0 + e);
            v = make_float4(P0[i4.x], P0[i4.y], P0[i4.z], P0[i4.w]);
        } else if (e < 2 * E_EDGES) {
            const int4 i4 = *reinterpret_cast<const int4*>(ei1 + (e - E_EDGES));
            v = make_float4(P1[i4.x], P1[i4.y], P1[i4.z], P1[i4.w]);
        } else if (e < 2 * E_EDGES + ES) {
            const int4 i4 = *reinterpret_cast<const int4*>(nh0 + (e - 2 * E_EDGES));
            v = make_float4(P2[i4.x], P2[i4.y], P2[i4.z], P2[i4.w]);
        } else if (e < 2 * E_EDGES + 2 * ES) {
            const int4 i4 = *reinterpret_cast<const int4*>(nh1 + (e - 2 * E_EDGES - ES));
            v = make_float4(P3[i4.x], P3[i4.y], P3[i4.z], P3[i4.w]);
        } else if (e < 2 * E_EDGES + 3 * ES) {
            const int i = e - 2 * E_EDGES - 2 * ES;
            const float s = P4[nt0[(i >> 4) << 4]];
            v = make_float4(s, s, s, s);
        } else {
            const int i = e - 2 * E_EDGES - 3 * ES;
            const float s = PB[nt1[(i >> 4) << 4]];
            v = make_float4(s, s, s, s);
        }
        *reinterpret_cast<float4*>(out + e) = v;
    }
}

extern "C" void kernel_launch(void* const* d_in, const int* in_sizes, int n_in,
                              void* d_out, int out_size, void* d_ws, size_t ws_size,
                              hipStream_t stream) {
    const float* embA = (const float*)d_in[0];
    const float* embB = (const float*)d_in[1];
    const float* rel  = (const float*)d_in[2];
    const int* ei0 = (const int*)d_in[3];
    const int* ei1 = (const int*)d_in[4];
    const int* nh0 = (const int*)d_in[5];
    const int* nh1 = (const int*)d_in[6];
    const int* nt0 = (const int*)d_in[7];
    const int* nt1 = (const int*)d_in[8];
    float* out = (float*)d_out;

    uint32_t* partA = (uint32_t*)d_ws;                        // 76*HW
    uint32_t* partB = partA + (size_t)2 * ACH * HW;           // 34*HW
    float* cntA = (float*)(partB + (size_t)BCH * HW);         // 4*N_A
    float* cntB = cntA + (size_t)4 * N_A;                     // 2*N_B
    float* svec = cntB + (size_t)2 * N_B;                     // NCPY*6*D
    float* cvec = svec + (size_t)NCPY * 6 * D;                // 6*D
    float* PA   = cvec + 6 * D;                               // 5*N_A (SoA)
    float* PB   = PA + (size_t)5 * N_A;                       // N_B

    k_hist<<<2 * ACH + BCH, 512, 0, stream>>>(ei0, ei1, nh0, nh1, nt0, nt1,
                                              partA, partB, svec);
    k_reduceC<<<(N_A + N_B + 255) / 256, 256, 0, stream>>>(partA, partB,
                                                           (float4*)cntA, (float2*)cntB);
    k_scan1<<<GA1 + GB1, 256, 0, stream>>>(embA, embB, cntA, cntB, svec);
    k_cvec<<<1, 256, 0, stream>>>(rel, svec, cvec);
    k_scan2<<<GA2 + GB2, 256, 0, stream>>>(embA, embB, cvec, PA, PB);
    k_scatter<<<2048, 256, 0, stream>>>(ei0, ei1, nh0, nh1, nt0, nt1, PA, PB, out);
}